// Round 7
// baseline (254.869 us; speedup 1.0000x reference)
//
#include <hip/hip_runtime.h>

#define LL 8192
#define HH 128

typedef __attribute__((ext_vector_type(8))) short short8v;
typedef __attribute__((ext_vector_type(4))) short short4v;
typedef __attribute__((ext_vector_type(4))) float f32x4;

__device__ inline short f2bf(float f) {
    union { float f; unsigned u; } x; x.f = f;
    unsigned r = (x.u + 0x7fffu + ((x.u >> 16) & 1u)) >> 16;
    return (short)r;
}
__device__ inline float bf2f(short s) {
    union { unsigned u; float f; } x; x.u = ((unsigned)(unsigned short)s) << 16;
    return x.f;
}

// LN of one 128-float LDS row across a full wave (2 elems/lane) -> packed 2xbf16
__device__ inline unsigned ln_pack(const float* rowF, int lane) {
    float2 xv = *(const float2*)&rowF[lane * 2];
    float s = xv.x + xv.y, s2 = xv.x * xv.x + xv.y * xv.y;
#pragma unroll
    for (int off = 32; off >= 1; off >>= 1) {
        s  += __shfl_xor(s,  off, 64);
        s2 += __shfl_xor(s2, off, 64);
    }
    float mu = s * (1.f / 128.f);
    float var = s2 * (1.f / 128.f) - mu * mu;
    float rstd = rsqrtf(var + 1e-5f);
    unsigned lo = (unsigned short)f2bf((xv.x - mu) * rstd);
    unsigned hi = (unsigned short)f2bf((xv.y - mu) * rstd);
    return lo | (hi << 16);
}

// ---------------------------------------------------------------------------
// one repack kernel: conv w -> bf16 [lay][k][o][i]; stacked QKV bf16 (+scale);
// b3; Wff bf16; zero the 8-row halo pads of both nb ping-pong buffers.
// ---------------------------------------------------------------------------
__global__ __launch_bounds__(256) void repack_all(const float* __restrict__ w,
                                                  const float* __restrict__ Wq,
                                                  const float* __restrict__ Wk,
                                                  const float* __restrict__ Wv,
                                                  const float* __restrict__ bq,
                                                  const float* __restrict__ bk,
                                                  const float* __restrict__ bv,
                                                  const float* __restrict__ Wff,
                                                  short* __restrict__ wkb,
                                                  short* __restrict__ wqkvb,
                                                  float* __restrict__ b3,
                                                  short* __restrict__ wffb,
                                                  unsigned* __restrict__ nbA_u,
                                                  unsigned* __restrict__ nbB_u) {
    const float qs = 0.08838834764831845f;
    int idx = blockIdx.x * 256 + threadIdx.x;
    if (idx < 458752) {                       // 4*128*128*7 conv weights
        int k = idx % 7;
        int t = idx / 7;
        int i = t % HH; t /= HH;
        int o = t % HH;
        int lay = t / HH;
        wkb[((lay * 7 + k) * HH + o) * HH + i] = f2bf(w[idx]);
    } else {
        int j = idx - 458752;
        if (j < 49152) {                      // stacked QKV weights
            int t = j >> 14, r = j & 16383;
            float v = (t == 0) ? Wq[r] * qs : (t == 1) ? Wk[r] : Wv[r];
            wqkvb[j] = f2bf(v);
        } else if (j < 49536) {               // stacked biases
            int jj = j - 49152;
            b3[jj] = (jj < 128) ? bq[jj] * qs : (jj < 256) ? bk[jj - 128] : bv[jj - 256];
        } else if (j < 65920) {               // FF weights
            wffb[j - 49536] = f2bf(Wff[j - 49536]);
        } else if (j < 65920 + 2048) {        // nb halo pads (8 rows each end, x2 bufs)
            int p = j - 65920;
            int u = p & 511, which = p >> 9;
            // front pad = uints [0,512); back pad starts at (8+LL)*128/2 = 524800
            unsigned* base = (which < 2) ? nbA_u : nbB_u;
            base[(which & 1) ? (524800 + u) : u] = 0u;
        }
    }
}

// ---------------------------------------------------------------------------
// init: h = x + pos_encoding (fp32), nb = LN(h) (bf16, padded). 1 wave/row.
// ---------------------------------------------------------------------------
__global__ __launch_bounds__(256) void pos_ln_kernel(const float* __restrict__ x,
                                                     float* __restrict__ h,
                                                     short* __restrict__ nbp) {
    int wave = threadIdx.x >> 6, lane = threadIdx.x & 63;
    int row = blockIdx.x * 4 + wave;
    int i0 = lane * 2;
    // pe: even index i0 and odd i0+1 share exponent e = i0/128
    float e = (float)i0 * (1.f / 128.f);
    float denom = powf(10000.f, e);
    float ang = (float)row / denom;
    float sv = sinf(ang), cv = cosf(ang);
    float2 xv = *(const float2*)&x[row * HH + i0];
    float h0 = xv.x + sv, h1 = xv.y + cv;
    *(float2*)&h[row * HH + i0] = make_float2(h0, h1);
    float s = h0 + h1, s2 = h0 * h0 + h1 * h1;
#pragma unroll
    for (int off = 32; off >= 1; off >>= 1) {
        s  += __shfl_xor(s,  off, 64);
        s2 += __shfl_xor(s2, off, 64);
    }
    float mu = s * (1.f / 128.f);
    float var = s2 * (1.f / 128.f) - mu * mu;
    float rstd = rsqrtf(var + 1e-5f);
    unsigned lo = (unsigned short)f2bf((h0 - mu) * rstd);
    unsigned hi = (unsigned short)f2bf((h1 - mu) * rstd);
    ((unsigned*)&nbp[row * HH])[lane] = lo | (hi << 16);
}

// ---------------------------------------------------------------------------
// per-layer conv: h += conv(nb_in) + bias  (in place), then nb_out = LN(h).
// A-frags straight from padded global nb (zero halo -> no guards, no staging
// barriers). One barrier total (before the LN exchange).
// wave = 16 rows x 32 cols; grid 512 x 4 waves.
// ---------------------------------------------------------------------------
__global__ __launch_bounds__(256) void conv_ln_kernel(const short* __restrict__ nbp_in,
                                                      const short* __restrict__ wkl,
                                                      const float* __restrict__ bias,
                                                      float* __restrict__ h,
                                                      short* __restrict__ nbp_out) {
    __shared__ float sF[16][132];
    int tid = threadIdx.x;
    int w = tid >> 6, lane = tid & 63;
    int l15 = lane & 15, quad = lane >> 4;
    int m0 = blockIdx.x * 16;
    int c0 = w * 32;

    f32x4 acc0 = (f32x4)(0.f), acc1 = (f32x4)(0.f);
#pragma unroll
    for (int k = 0; k < 7; k++) {
        const short* ar = nbp_in + (m0 + l15 + k - 3) * HH;
        const short* b0 = wkl + (k * HH + c0 + l15) * HH;
        const short* b1 = b0 + 16 * HH;
#pragma unroll
        for (int ks = 0; ks < 4; ks++) {
            short8v af  = *(const short8v*)&ar[ks * 32 + quad * 8];
            short8v bf0 = *(const short8v*)&b0[ks * 32 + quad * 8];
            short8v bf1 = *(const short8v*)&b1[ks * 32 + quad * 8];
            acc0 = __builtin_amdgcn_mfma_f32_16x16x32_bf16(af, bf0, acc0, 0, 0, 0);
            acc1 = __builtin_amdgcn_mfma_f32_16x16x32_bf16(af, bf1, acc1, 0, 0, 0);
        }
    }
    float bb0 = bias[c0 + l15], bb1 = bias[c0 + 16 + l15];
#pragma unroll
    for (int r = 0; r < 4; r++) {
        int rowL = quad * 4 + r;
        int g = (m0 + rowL) * HH;
        float z0 = h[g + c0 + l15]      + acc0[r] + bb0;
        float z1 = h[g + c0 + 16 + l15] + acc1[r] + bb1;
        h[g + c0 + l15]      = z0;
        h[g + c0 + 16 + l15] = z1;
        sF[rowL][c0 + l15]      = z0;
        sF[rowL][c0 + 16 + l15] = z1;
    }
    __syncthreads();
#pragma unroll
    for (int rr = 0; rr < 4; rr++) {
        int rowL = w * 4 + rr;
        unsigned packed = ln_pack(&sF[rowL][0], lane);
        ((unsigned*)&nbp_out[(m0 + rowL) * HH])[lane] = packed;
    }
}

// ---------------------------------------------------------------------------
// QKV gemm from LN'd nb. q,k row-major bf16; v transposed [d][L] via LDS.
// ---------------------------------------------------------------------------
__global__ __launch_bounds__(256) void qkv_kernel(const short* __restrict__ nbp,
                                                  const short* __restrict__ wqkvb,
                                                  const float* __restrict__ b3,
                                                  short* __restrict__ qb,
                                                  short* __restrict__ kb,
                                                  short* __restrict__ vt) {
    __shared__ short sT[4][32][17];
    int tid = threadIdx.x;
    int w = tid >> 6, lane = tid & 63;
    int l15 = lane & 15, quad = lane >> 4;
    int m0 = blockIdx.x * 16;
    int c0 = w * 32;

    short8v af4[4];
#pragma unroll
    for (int ks = 0; ks < 4; ks++)
        af4[ks] = *(const short8v*)&nbp[(m0 + l15) * HH + ks * 32 + quad * 8];

    for (int t = 0; t < 3; t++) {
        f32x4 acc0 = (f32x4)(0.f), acc1 = (f32x4)(0.f);
        const short* b0 = wqkvb + (t * 128 + c0 + l15) * HH;
        const short* b1 = b0 + 16 * HH;
#pragma unroll
        for (int ks = 0; ks < 4; ks++) {
            short8v bf0 = *(const short8v*)&b0[ks * 32 + quad * 8];
            short8v bf1 = *(const short8v*)&b1[ks * 32 + quad * 8];
            acc0 = __builtin_amdgcn_mfma_f32_16x16x32_bf16(af4[ks], bf0, acc0, 0, 0, 0);
            acc1 = __builtin_amdgcn_mfma_f32_16x16x32_bf16(af4[ks], bf1, acc1, 0, 0, 0);
        }
        float bb0 = b3[t * 128 + c0 + l15], bb1 = b3[t * 128 + c0 + 16 + l15];
        if (t < 2) {
            short* o = (t == 0) ? qb : kb;
#pragma unroll
            for (int r = 0; r < 4; r++) {
                int lr = m0 + quad * 4 + r;
                o[lr * HH + c0 + l15]      = f2bf(acc0[r] + bb0);
                o[lr * HH + c0 + 16 + l15] = f2bf(acc1[r] + bb1);
            }
        } else {
#pragma unroll
            for (int r = 0; r < 4; r++) {
                sT[w][l15][quad * 4 + r]      = f2bf(acc0[r] + bb0);
                sT[w][16 + l15][quad * 4 + r] = f2bf(acc1[r] + bb1);
            }
            asm volatile("s_waitcnt lgkmcnt(0)" ::: "memory");
#pragma unroll
            for (int cc = 0; cc < 8; cc++) {
                int col = cc * 4 + quad;
                vt[(c0 + col) * LL + m0 + l15] = sT[w][col][l15];
            }
        }
    }
}

// ---------------------------------------------------------------------------
// bf16 MFMA flash attention: 128 q-rows/block (4 waves x 32), KV chunk (64
// rows) staged per block into LDS in fragment-major order, register prefetch.
// KV split nsplit-way across blockIdx.y. No-max softmax, bf16 partials out.
// ---------------------------------------------------------------------------
#define FBN 64

__global__ __launch_bounds__(256, 2) void flash_mfma_kernel(const short* __restrict__ qs,
                                                            const short* __restrict__ ksrc,
                                                            const short* __restrict__ vsrc,
                                                            short* __restrict__ PO,
                                                            float* __restrict__ Pl,
                                                            int segrows) {
    __shared__ short sK[16 * 64 * 8];   // fragment-major, 16 KB
    __shared__ short sV[16 * 64 * 8];
    __shared__ short sP[4][32][72];     // per-wave P tiles

    const int tid = threadIdx.x;
    const int w = tid >> 6, lane = tid & 63;
    const int l15 = lane & 15, quad = lane >> 4;
    const int m0 = blockIdx.x * 128;
    const int seg = blockIdx.y;
    const int jbeg = seg * segrows;
    const int nchunk = segrows >> 6;

    const int vdt_base = (w >> 1);
    const int vks2 = w & 1;

    short8v qf[2][4];
#pragma unroll
    for (int mt = 0; mt < 2; mt++)
#pragma unroll
        for (int ks = 0; ks < 4; ks++)
            qf[mt][ks] = *(const short8v*)&qs[(m0 + w * 32 + mt * 16 + l15) * HH + ks * 32 + quad * 8];

    float l_r[2][4] = {{0.f, 0.f, 0.f, 0.f}, {0.f, 0.f, 0.f, 0.f}};
    f32x4 o_acc[2][8];
#pragma unroll
    for (int mt = 0; mt < 2; mt++)
#pragma unroll
        for (int dt = 0; dt < 8; dt++) o_acc[mt][dt] = (f32x4)(0.f);

    short8v kr[4], vr[4];
#pragma unroll
    for (int r = 0; r < 4; r++) {
        kr[r] = *(const short8v*)&ksrc[(jbeg + r * 16 + l15) * HH + w * 32 + quad * 8];
        vr[r] = *(const short8v*)&vsrc[((2 * r + vdt_base) * 16 + l15) * LL + jbeg + vks2 * 32 + quad * 8];
    }

    for (int c = 0; c < nchunk; c++) {
        __syncthreads();
#pragma unroll
        for (int r = 0; r < 4; r++) {
            *(short8v*)&sK[((w + 4 * r) * 64 + lane) * 8] = kr[r];
            *(short8v*)&sV[((w + 4 * r) * 64 + lane) * 8] = vr[r];
        }
        __syncthreads();
        if (c + 1 < nchunk) {
            const int j1 = jbeg + (c + 1) * FBN;
#pragma unroll
            for (int r = 0; r < 4; r++) {
                kr[r] = *(const short8v*)&ksrc[(j1 + r * 16 + l15) * HH + w * 32 + quad * 8];
                vr[r] = *(const short8v*)&vsrc[((2 * r + vdt_base) * 16 + l15) * LL + j1 + vks2 * 32 + quad * 8];
            }
        }
        // ---- S = Q K^T ----
        f32x4 s_acc[2][4];
#pragma unroll
        for (int mt = 0; mt < 2; mt++)
#pragma unroll
            for (int nt = 0; nt < 4; nt++) s_acc[mt][nt] = (f32x4)(0.f);
#pragma unroll
        for (int nt = 0; nt < 4; nt++)
#pragma unroll
            for (int ks = 0; ks < 4; ks++) {
                short8v kf = *(const short8v*)&sK[((nt * 4 + ks) * 64 + lane) * 8];
                s_acc[0][nt] = __builtin_amdgcn_mfma_f32_16x16x32_bf16(qf[0][ks], kf, s_acc[0][nt], 0, 0, 0);
                s_acc[1][nt] = __builtin_amdgcn_mfma_f32_16x16x32_bf16(qf[1][ks], kf, s_acc[1][nt], 0, 0, 0);
            }
        // ---- p = exp(s); per-lane row-sums; truncating bf16 pack to LDS ----
#pragma unroll
        for (int mt = 0; mt < 2; mt++)
#pragma unroll
            for (int nt = 0; nt < 4; nt++)
#pragma unroll
                for (int r = 0; r < 4; r++) {
                    float p = __expf(fminf(s_acc[mt][nt][r], 30.f));
                    l_r[mt][r] += p;
                    union { float f; unsigned u; } cv; cv.f = p;
                    sP[w][mt * 16 + quad * 4 + r][nt * 16 + l15] = (short)(cv.u >> 16);
                }
        asm volatile("s_waitcnt lgkmcnt(0)" ::: "memory");
        // ---- O += P V ----
#pragma unroll
        for (int ks2 = 0; ks2 < 2; ks2++) {
            short8v pf0 = *(const short8v*)&sP[w][l15][ks2 * 32 + quad * 8];
            short8v pf1 = *(const short8v*)&sP[w][16 + l15][ks2 * 32 + quad * 8];
#pragma unroll
            for (int dt = 0; dt < 8; dt++) {
                short8v vf = *(const short8v*)&sV[((dt * 2 + ks2) * 64 + lane) * 8];
                o_acc[0][dt] = __builtin_amdgcn_mfma_f32_16x16x32_bf16(pf0, vf, o_acc[0][dt], 0, 0, 0);
                o_acc[1][dt] = __builtin_amdgcn_mfma_f32_16x16x32_bf16(pf1, vf, o_acc[1][dt], 0, 0, 0);
            }
        }
    }
    // ---- finalize l, write partials ----
#pragma unroll
    for (int mt = 0; mt < 2; mt++)
#pragma unroll
        for (int r = 0; r < 4; r++) {
            float v = l_r[mt][r];
            v += __shfl_xor(v, 1, 64);
            v += __shfl_xor(v, 2, 64);
            v += __shfl_xor(v, 4, 64);
            v += __shfl_xor(v, 8, 64);
            if (l15 == 0)
                Pl[seg * LL + m0 + w * 32 + mt * 16 + quad * 4 + r] = v;
        }
#pragma unroll
    for (int mt = 0; mt < 2; mt++)
#pragma unroll
        for (int dt = 0; dt < 8; dt++)
#pragma unroll
            for (int r = 0; r < 4; r++)
                PO[(size_t)seg * LL * HH + (m0 + w * 32 + mt * 16 + quad * 4 + r) * HH + dt * 16 + l15] =
                    f2bf(o_acc[mt][dt][r]);
}

// ---------------------------------------------------------------------------
// fused attention-merge + residual + LN + FF gemm + relu + residual -> out
// ---------------------------------------------------------------------------
__global__ __launch_bounds__(256) void ff_kernel(const float* __restrict__ hin,
                                                 const short* __restrict__ PO,
                                                 const float* __restrict__ Pl,
                                                 const short* __restrict__ wffb,
                                                 const float* __restrict__ bff,
                                                 float* __restrict__ out,
                                                 int nsplit) {
    __shared__ float sF[16][132];
    __shared__ short sA[16][136];
    __shared__ float sLi[16];
    int tid = threadIdx.x;
    int w = tid >> 6, lane = tid & 63;
    int l15 = lane & 15, quad = lane >> 4;
    int m0 = blockIdx.x * 16;

    if (tid < 16) {
        float s = 0.f;
        for (int seg = 0; seg < nsplit; seg++) s += Pl[seg * LL + m0 + tid];
        sLi[tid] = 1.f / s;
    }
    __syncthreads();
    for (int idx = tid; idx < 16 * 32; idx += 256) {
        int r = idx >> 5, c4 = (idx & 31) << 2;
        float4 hv = *(const float4*)&hin[(m0 + r) * HH + c4];
        float s0 = 0.f, s1 = 0.f, s2 = 0.f, s3 = 0.f;
        for (int seg = 0; seg < nsplit; seg++) {
            short4v pv = *(const short4v*)&PO[(size_t)seg * LL * HH + (m0 + r) * HH + c4];
            s0 += bf2f(pv[0]); s1 += bf2f(pv[1]); s2 += bf2f(pv[2]); s3 += bf2f(pv[3]);
        }
        float li = sLi[r];
        *(float4*)&sF[r][c4] = make_float4(hv.x + s0 * li, hv.y + s1 * li,
                                           hv.z + s2 * li, hv.w + s3 * li);
    }
    __syncthreads();
#pragma unroll
    for (int rr = 0; rr < 4; rr++) {
        int row = rr * 4 + w;
        ((unsigned*)&sA[row][0])[lane] = ln_pack(&sF[row][0], lane);
    }
    __syncthreads();
    int c0 = w * 32;
    f32x4 acc0 = (f32x4)(0.f), acc1 = (f32x4)(0.f);
    const short* b0 = wffb + (c0 + l15) * HH;
    const short* b1 = b0 + 16 * HH;
#pragma unroll
    for (int ks = 0; ks < 4; ks++) {
        short8v af = *(const short8v*)&sA[l15][ks * 32 + quad * 8];
        short8v bf0 = *(const short8v*)&b0[ks * 32 + quad * 8];
        short8v bf1 = *(const short8v*)&b1[ks * 32 + quad * 8];
        acc0 = __builtin_amdgcn_mfma_f32_16x16x32_bf16(af, bf0, acc0, 0, 0, 0);
        acc1 = __builtin_amdgcn_mfma_f32_16x16x32_bf16(af, bf1, acc1, 0, 0, 0);
    }
    float bb0 = bff[c0 + l15], bb1 = bff[c0 + 16 + l15];
#pragma unroll
    for (int r = 0; r < 4; r++) {
        int lr = quad * 4 + r;
        out[(m0 + lr) * HH + c0 + l15]      = fmaxf(acc0[r] + bb0, 0.f) + sF[lr][c0 + l15];
        out[(m0 + lr) * HH + c0 + 16 + l15] = fmaxf(acc1[r] + bb1, 0.f) + sF[lr][c0 + 16 + l15];
    }
}

// ---------------------------------------------------------------------------
extern "C" void kernel_launch(void* const* d_in, const int* in_sizes, int n_in,
                              void* d_out, int out_size, void* d_ws, size_t ws_size,
                              hipStream_t stream) {
    const float* x      = (const float*)d_in[0];
    const float* conv_w = (const float*)d_in[1];
    const float* conv_b = (const float*)d_in[2];
    const float* Wq = (const float*)d_in[3];
    const float* bq = (const float*)d_in[4];
    const float* Wk = (const float*)d_in[5];
    const float* bk = (const float*)d_in[6];
    const float* Wv = (const float*)d_in[7];
    const float* bv = (const float*)d_in[8];
    const float* Wff = (const float*)d_in[9];
    const float* bff = (const float*)d_in[10];
    float* out = (float*)d_out;

    char* ws = (char*)d_ws;
    const size_t MB = 1u << 20;
    float* h    = (float*)(ws);                        // 4 MB, alive to end
    short* qb   = (short*)(ws + 4 * MB);               // 2 MB
    short* kb   = (short*)(ws + 6 * MB);               // 2 MB
    short* vt   = (short*)(ws + 8 * MB);               // 2 MB
    float* Pl   = (float*)(ws + 10 * MB);              // <=512 KB
    short* wffb = (short*)(ws + 10 * MB + 524288);     // 32 KB (alive till ff)
    short* PO   = (short*)(ws + 11 * MB);              // 16 or 32 MB bf16 partials
    // dead-before-flash buffers aliased inside the PO span:
    short* nbA_all = (short*)(ws + 11 * MB);           // (8192+16)*128*2 = 2.004 MB
    short* nbB_all = (short*)(ws + 11 * MB + 2621440); // +2.5 MB
    short* wkb     = (short*)(ws + 16 * MB);           // 896 KB
    short* wqkvb   = (short*)(ws + 17 * MB);           // 96 KB
    float* b3      = (float*)(ws + 17 * MB + 131072);  // 1.5 KB
    short* nbA = nbA_all + 8 * HH;                     // real rows after 8-row pad
    short* nbB = nbB_all + 8 * HH;

    int nsplit = (ws_size >= (size_t)44 * MB) ? 16 : 8;
    int segrows = LL / nsplit;

    repack_all<<<2058, 256, 0, stream>>>(conv_w, Wq, Wk, Wv, bq, bk, bv, Wff,
                                         wkb, wqkvb, b3, wffb,
                                         (unsigned*)nbA_all, (unsigned*)nbB_all);
    pos_ln_kernel<<<LL / 4, 256, 0, stream>>>(x, h, nbA);

    const int KW = 7 * HH * HH;
    conv_ln_kernel<<<LL / 16, 256, 0, stream>>>(nbA, wkb + 0 * KW, conv_b + 0 * HH, h, nbB);
    conv_ln_kernel<<<LL / 16, 256, 0, stream>>>(nbB, wkb + 1 * KW, conv_b + 1 * HH, h, nbA);
    conv_ln_kernel<<<LL / 16, 256, 0, stream>>>(nbA, wkb + 2 * KW, conv_b + 2 * HH, h, nbB);
    conv_ln_kernel<<<LL / 16, 256, 0, stream>>>(nbB, wkb + 3 * KW, conv_b + 3 * HH, h, nbA);

    qkv_kernel<<<LL / 16, 256, 0, stream>>>(nbA, wqkvb, b3, qb, kb, vt);

    flash_mfma_kernel<<<dim3(LL / 128, nsplit), 256, 0, stream>>>(qb, kb, vt, PO, Pl, segrows);

    ff_kernel<<<LL / 16, 256, 0, stream>>>(h, PO, Pl, wffb, bff, out, nsplit);
}